// Round 8
// baseline (328.164 us; speedup 1.0000x reference)
//
#include <hip/hip_runtime.h>
#include <hip/hip_bf16.h>
#include <hip/hip_cooperative_groups.h>
#include <cstdint>

namespace cg = cooperative_groups;

// Problem constants (features: [512, 16, 512] fp32 -> N=8192 rows, D=512)
#define N_TOT 8192
#define DDIM  512
#define DBYTES 512                     // bytes per row in fp8
#define NBLK  64                       // 8192 / 128 tile blocks per dim
#define NTRI  (NBLK * (NBLK + 1) / 2)  // 2080 lower-triangle blocks
#define GRIDB 512                      // persistent blocks (2 per CU, exact fit)
constexpr float INV_T = 1.0f / 0.07f;

typedef uint8_t u8;
typedef __attribute__((ext_vector_type(8))) int i32x8_t;
typedef __attribute__((ext_vector_type(4))) float f32x4_t;

// ---- helpers ---------------------------------------------------------------

__device__ __forceinline__ void load16_to_lds(const void* g, void* l) {
  __builtin_amdgcn_global_load_lds(
      (const __attribute__((address_space(1))) unsigned int*)g,
      (__attribute__((address_space(3))) unsigned int*)l, 16, 0, 0);
}

#define WAIT_VMCNT(n)                                     \
  do {                                                    \
    asm volatile("s_waitcnt vmcnt(" #n ")" ::: "memory"); \
  } while (0)

template <int CTRL>
__device__ __forceinline__ float dpp_shr_add(float v) {
  int sh = __builtin_amdgcn_update_dpp(0, __builtin_bit_cast(int, v),
                                       CTRL, 0xF, 0xF, true);
  return v + __builtin_bit_cast(float, sh);
}
#define DPP_ROW_SHR1 0x111
#define DPP_ROW_SHR2 0x112
#define DPP_ROW_SHR4 0x114
#define DPP_ROW_SHR8 0x118

__device__ __forceinline__ int tri_decode_bi(int k) {
  int bi = (int)((sqrtf(8.0f * (float)k + 1.0f) - 1.0f) * 0.5f);
  while ((bi + 1) * (bi + 2) / 2 <= k) ++bi;
  while (bi * (bi + 1) / 2 > k) --bi;
  return bi;
}

// normalize one row (wave-wide): fp32 -> unit-norm fp8 e4m3
__device__ __forceinline__ void normalize_row(const float* __restrict__ X,
                                              u8* __restrict__ Xn, int row,
                                              int lane) {
  const float4* xr = (const float4*)(X + (size_t)row * DDIM);
  float4 v0 = xr[lane];
  float4 v1 = xr[lane + 64];
  float s = v0.x * v0.x + v0.y * v0.y + v0.z * v0.z + v0.w * v0.w
          + v1.x * v1.x + v1.y * v1.y + v1.z * v1.z + v1.w * v1.w;
#pragma unroll
  for (int m = 1; m < 64; m <<= 1) s += __shfl_xor(s, m);
  const float scale = 1.0f / fmaxf(sqrtf(s), 1e-8f);
  int w0 = __builtin_amdgcn_cvt_pk_fp8_f32(v0.x * scale, v0.y * scale, 0, 0);
  w0     = __builtin_amdgcn_cvt_pk_fp8_f32(v0.z * scale, v0.w * scale, w0, 1);
  int w1 = __builtin_amdgcn_cvt_pk_fp8_f32(v1.x * scale, v1.y * scale, 0, 0);
  w1     = __builtin_amdgcn_cvt_pk_fp8_f32(v1.z * scale, v1.w * scale, w1, 1);
  uint32_t* orow = (uint32_t*)(Xn + (size_t)row * DBYTES);
  orow[lane]      = (uint32_t)w0;
  orow[lane + 64] = (uint32_t)w1;
}

// ---- fused kernel: normalize | grid.sync | tri-GEMM+exp-sums | finalize ----
//
// R8: ONE COOPERATIVE KERNEL. Measured across R0..R7: total - gemm = 58-65us
// CONSTANT while gemm varied 56..94 -> the inter-kernel overhead (3 graph
// launches + boundary flushes + small kernels) is the dominant remaining
// cost. Fuse all phases; grid.sync() between them (harness supports
// hipLaunchCooperativeKernel). 512 blocks x 256 thr, 64KB LDS = exactly
// 2 blocks/CU co-resident.
//
// Coherence across phases (per-XCD L2s non-coherent): writers do
// __threadfence() (L2 writeback) before grid.sync(); phase-3 reads tsum via
// atomicAdd(p,0) -- device-coherent read, dodging this block's own stale
// zeroed lines from phase 1. Readers of Xn never touched it before phase 2,
// so cold misses fetch fresh data.
//
// Phase 2 = R7's persistent gemm verbatim (measured 56.9us): 128x128 tiles,
// 4 waves in 2x2, 64x64/wave via 4x4 frags of mfma_scale 16x16x128 f8f6f4
// (e4m3, unit scales 0x7F), dbuf 64KB, counted vmcnt(8) chunk pipeline,
// XOR-swizzled LDS (granule (row,j) at slot row*8+(j^(row&7)), swizzle
// inverted on global src).
__global__ __launch_bounds__(256, 2) void fused_kernel(const float* __restrict__ X,
                                                       u8* __restrict__ Xn,
                                                       float* __restrict__ tsum,
                                                       float* __restrict__ out) {
  __shared__ __align__(16) u8 sA[2][128 * 128];  // 2 x 16 KB
  __shared__ __align__(16) u8 sB[2][128 * 128];  // 2 x 16 KB

  cg::grid_group grid = cg::this_grid();

  const int tid  = threadIdx.x;   // 0..255
  const int lane = tid & 63;
  const int wv   = tid >> 6;      // wave 0..3

  // ---- phase 1: normalize 16 rows/block + zero tsum/out ----
  {
    const int rbase = blockIdx.x * 16 + wv * 4;
#pragma unroll
    for (int i = 0; i < 4; ++i) normalize_row(X, Xn, rbase + i, lane);
    if (tid < 16) tsum[blockIdx.x * 16 + tid] = 0.0f;
    if (blockIdx.x == 0 && tid == 0) out[0] = 0.0f;
  }
  __threadfence();  // write back dirty L2 lines to device-coherent point
  grid.sync();

  // ---- phase 2: persistent triangular GEMM + fused exp row/col sums ----
  {
    const int l15  = lane & 15;
    const int quad = lane >> 4;
    const int wm   = wv >> 1;
    const int wn   = wv & 1;

    const int srow = tid >> 3;
    const int goff = ((tid & 7) ^ (srow & 7)) * 16;

    int tt = blockIdx.x;
    int bi = tri_decode_bi(tt);
    int bj = tt - bi * (bi + 1) / 2;
    const u8* gA = Xn + (size_t)(bi * 128 + srow) * DBYTES + goff;
    const u8* gB = Xn + (size_t)(bj * 128 + srow) * DBYTES + goff;

#define ISSUE(PA, PB, KB, BUF)                                                \
  do {                                                                        \
    _Pragma("unroll") for (int r = 0; r < 4; ++r) {                           \
      load16_to_lds((PA) + (size_t)(r * 32) * DBYTES + (KB),                  \
                    sA[BUF] + tid * 16 + r * 4096);                           \
      load16_to_lds((PB) + (size_t)(r * 32) * DBYTES + (KB),                  \
                    sB[BUF] + tid * 16 + r * 4096);                           \
    }                                                                         \
  } while (0)

#define COMPUTE(BUF)                                                          \
  do {                                                                        \
    i32x8_t a[4], b[4];                                                       \
    _Pragma("unroll") for (int mi = 0; mi < 4; mi++) {                        \
      const int row = wm * 64 + mi * 16 + l15;                                \
      const int s0 = ((quad * 2) ^ (row & 7)) * 16;                           \
      const int s1 = ((quad * 2 + 1) ^ (row & 7)) * 16;                       \
      int4 lo = *(const int4*)&sA[BUF][row * 128 + s0];                       \
      int4 hi = *(const int4*)&sA[BUF][row * 128 + s1];                       \
      a[mi] = (i32x8_t){lo.x, lo.y, lo.z, lo.w, hi.x, hi.y, hi.z, hi.w};      \
    }                                                                         \
    _Pragma("unroll") for (int ni = 0; ni < 4; ni++) {                        \
      const int row = wn * 64 + ni * 16 + l15;                                \
      const int s0 = ((quad * 2) ^ (row & 7)) * 16;                           \
      const int s1 = ((quad * 2 + 1) ^ (row & 7)) * 16;                       \
      int4 lo = *(const int4*)&sB[BUF][row * 128 + s0];                       \
      int4 hi = *(const int4*)&sB[BUF][row * 128 + s1];                       \
      b[ni] = (i32x8_t){lo.x, lo.y, lo.z, lo.w, hi.x, hi.y, hi.z, hi.w};      \
    }                                                                         \
    __builtin_amdgcn_s_setprio(1);                                            \
    _Pragma("unroll") for (int mi = 0; mi < 4; mi++)                          \
        _Pragma("unroll") for (int ni = 0; ni < 4; ni++)                      \
            acc[mi][ni] = __builtin_amdgcn_mfma_scale_f32_16x16x128_f8f6f4(   \
                a[mi], b[ni], acc[mi][ni], 0, 0, 0, 0x7F7F7F7Fu, 0,           \
                0x7F7F7F7Fu);                                                 \
    __builtin_amdgcn_s_setprio(0);                                            \
  } while (0)

    ISSUE(gA, gB, 0, 0);

    f32x4_t acc[4][4];
#pragma unroll
    for (int i = 0; i < 4; i++)
#pragma unroll
      for (int j = 0; j < 4; j++) acc[i][j] = {0.f, 0.f, 0.f, 0.f};

    for (;;) {
      const int rowBase = bi * 128;
      const int colBase = bj * 128;
      const bool isDiag = (bi == bj);

      const int tt2 = tt + GRIDB;
      const bool hasNext = (tt2 < NTRI);
      int bi2 = 0, bj2 = 0;
      const u8 *gA2 = Xn, *gB2 = Xn;
      if (hasNext) {
        bi2 = tri_decode_bi(tt2);
        bj2 = tt2 - bi2 * (bi2 + 1) / 2;
        gA2 = Xn + (size_t)(bi2 * 128 + srow) * DBYTES + goff;
        gB2 = Xn + (size_t)(bj2 * 128 + srow) * DBYTES + goff;
      }

#pragma unroll
      for (int c = 0; c < 4; ++c) {
        if (c < 3) {
          ISSUE(gA, gB, (c + 1) * 128, (c + 1) & 1);
          WAIT_VMCNT(8);
        } else if (hasNext) {
          ISSUE(gA2, gB2, 0, 0);
          WAIT_VMCNT(8);
        } else {
          WAIT_VMCNT(0);
        }
        __builtin_amdgcn_s_barrier();
        asm volatile("" ::: "memory");
        __builtin_amdgcn_sched_barrier(0);

        COMPUTE(c & 1);

        if (c == 3) {
          if (isDiag) {
#pragma unroll
            for (int mi = 0; mi < 4; mi++) {
#pragma unroll
              for (int r = 0; r < 4; r++) {
                const int row = rowBase + wm * 64 + mi * 16 + quad * 4 + r;
                float rs = 0.0f;
#pragma unroll
                for (int ni = 0; ni < 4; ni++) {
                  const int col = colBase + wn * 64 + ni * 16 + l15;
                  const float e = __expf((acc[mi][ni][r] - 1.0f) * INV_T);
                  rs += (row == col) ? 0.0f : e;
                }
                rs = dpp_shr_add<DPP_ROW_SHR1>(rs);
                rs = dpp_shr_add<DPP_ROW_SHR2>(rs);
                rs = dpp_shr_add<DPP_ROW_SHR4>(rs);
                rs = dpp_shr_add<DPP_ROW_SHR8>(rs);
                if (l15 == 15) atomicAdd(&tsum[row], rs);
              }
            }
          } else {
            float csum[4] = {0.f, 0.f, 0.f, 0.f};
#pragma unroll
            for (int mi = 0; mi < 4; mi++) {
#pragma unroll
              for (int r = 0; r < 4; r++) {
                const int row = rowBase + wm * 64 + mi * 16 + quad * 4 + r;
                float rs = 0.0f;
#pragma unroll
                for (int ni = 0; ni < 4; ni++) {
                  const float e = __expf((acc[mi][ni][r] - 1.0f) * INV_T);
                  rs += e;
                  csum[ni] += e;
                }
                rs = dpp_shr_add<DPP_ROW_SHR1>(rs);
                rs = dpp_shr_add<DPP_ROW_SHR2>(rs);
                rs = dpp_shr_add<DPP_ROW_SHR4>(rs);
                rs = dpp_shr_add<DPP_ROW_SHR8>(rs);
                if (l15 == 15) atomicAdd(&tsum[row], rs);
              }
            }
#pragma unroll
            for (int ni = 0; ni < 4; ni++) {
              csum[ni] += __shfl_xor(csum[ni], 16);
              csum[ni] += __shfl_xor(csum[ni], 32);
              if (quad == 0)
                atomicAdd(&tsum[colBase + wn * 64 + ni * 16 + l15], csum[ni]);
            }
          }
#pragma unroll
          for (int i = 0; i < 4; i++)
#pragma unroll
            for (int j = 0; j < 4; j++) acc[i][j] = {0.f, 0.f, 0.f, 0.f};
        }
        asm volatile("" ::: "memory");
        __builtin_amdgcn_s_barrier();
      }

      if (!hasNext) break;
      tt = tt2; bi = bi2; bj = bj2; gA = gA2; gB = gB2;
    }
#undef ISSUE
#undef COMPUTE
  }
  __threadfence();
  grid.sync();

  // ---- phase 3: loss = mean_i log1p(tsum_i), 16 entries/block ----
  {
    if (tid < 16) {
      // atomic read: device-coherent (this block's L2 may hold the stale
      // zeroed line it wrote in phase 1)
      float v = atomicAdd(&tsum[blockIdx.x * 16 + tid], 0.0f);
      float s = log1pf(v);
      s += __shfl_xor(s, 1);
      s += __shfl_xor(s, 2);
      s += __shfl_xor(s, 4);
      s += __shfl_xor(s, 8);
      if (tid == 0) atomicAdd(out, s * (1.0f / N_TOT));
    }
  }
}

// ---- fallback path (3 separate launches, R7-equivalent) --------------------
__global__ __launch_bounds__(256) void normalize_kernel(const float* __restrict__ X,
                                                        u8* __restrict__ Xn,
                                                        float* __restrict__ tsum,
                                                        float* __restrict__ out) {
  if (blockIdx.x < 32) tsum[blockIdx.x * 256 + threadIdx.x] = 0.0f;
  if (blockIdx.x == 32 && threadIdx.x == 0) out[0] = 0.0f;
  normalize_row(X, Xn, blockIdx.x * 4 + (threadIdx.x >> 6), threadIdx.x & 63);
}

__global__ __launch_bounds__(256) void finalize_kernel(const float* __restrict__ tsum,
                                                       float* __restrict__ out) {
  const int i = blockIdx.x * 256 + threadIdx.x;
  float s = log1pf(tsum[i]);
#pragma unroll
  for (int m = 1; m < 64; m <<= 1) s += __shfl_xor(s, m);
  __shared__ float ws[4];
  if ((threadIdx.x & 63) == 0) ws[threadIdx.x >> 6] = s;
  __syncthreads();
  if (threadIdx.x == 0)
    atomicAdd(out, (ws[0] + ws[1] + ws[2] + ws[3]) * (1.0f / N_TOT));
}

// minimal standalone gemm for fallback: reuse fused phase-2 via a wrapper is
// not possible (grid.sync) -- fallback uses the R0 2-phase kernel.
__global__ __launch_bounds__(256) void gemm_fallback(const u8* __restrict__ Xn,
                                                     float* __restrict__ tsum) {
  __shared__ __align__(16) u8 sA[128 * 128];
  __shared__ __align__(16) u8 sB[128 * 128];
  const int k = blockIdx.x;
  int bi = tri_decode_bi(k);
  const int bj = k - bi * (bi + 1) / 2;
  const int rowBase = bi * 128, colBase = bj * 128;
  const bool isDiag = (bi == bj);
  const int t = threadIdx.x, lane = t & 63, l15 = lane & 15, quad = lane >> 4;
  const int w = t >> 6, wm = w >> 1, wn = w & 1;
  f32x4_t acc[4][4];
#pragma unroll
  for (int i = 0; i < 4; i++)
#pragma unroll
    for (int j = 0; j < 4; j++) acc[i][j] = {0.f, 0.f, 0.f, 0.f};
  const int srow = t >> 3;
  const int goff = ((t & 7) ^ (srow & 7)) * 16;
  const u8* gA = Xn + (size_t)(rowBase + srow) * DBYTES + goff;
  const u8* gB = Xn + (size_t)(colBase + srow) * DBYTES + goff;
  u8* lA = sA + t * 16;
  u8* lB = sB + t * 16;
  for (int k0 = 0; k0 < DBYTES; k0 += 128) {
#pragma unroll
    for (int r = 0; r < 4; r++) {
      load16_to_lds(gA + (size_t)(r * 32) * DBYTES + k0, lA + r * 4096);
      load16_to_lds(gB + (size_t)(r * 32) * DBYTES + k0, lB + r * 4096);
    }
    __syncthreads();
    i32x8_t a[4], b[4];
#pragma unroll
    for (int mi = 0; mi < 4; mi++) {
      const int row = wm * 64 + mi * 16 + l15;
      const int s0 = ((quad * 2) ^ (row & 7)) * 16;
      const int s1 = ((quad * 2 + 1) ^ (row & 7)) * 16;
      int4 lo = *(const int4*)&sA[row * 128 + s0];
      int4 hi = *(const int4*)&sA[row * 128 + s1];
      a[mi] = (i32x8_t){lo.x, lo.y, lo.z, lo.w, hi.x, hi.y, hi.z, hi.w};
    }
#pragma unroll
    for (int ni = 0; ni < 4; ni++) {
      const int row = wn * 64 + ni * 16 + l15;
      const int s0 = ((quad * 2) ^ (row & 7)) * 16;
      const int s1 = ((quad * 2 + 1) ^ (row & 7)) * 16;
      int4 lo = *(const int4*)&sB[row * 128 + s0];
      int4 hi = *(const int4*)&sB[row * 128 + s1];
      b[ni] = (i32x8_t){lo.x, lo.y, lo.z, lo.w, hi.x, hi.y, hi.z, hi.w};
    }
#pragma unroll
    for (int mi = 0; mi < 4; mi++)
#pragma unroll
      for (int ni = 0; ni < 4; ni++)
        acc[mi][ni] = __builtin_amdgcn_mfma_scale_f32_16x16x128_f8f6f4(
            a[mi], b[ni], acc[mi][ni], 0, 0, 0, 0x7F7F7F7Fu, 0, 0x7F7F7F7Fu);
    __syncthreads();
  }
  if (isDiag) {
#pragma unroll
    for (int mi = 0; mi < 4; mi++)
#pragma unroll
      for (int r = 0; r < 4; r++) {
        const int row = rowBase + wm * 64 + mi * 16 + quad * 4 + r;
        float rs = 0.0f;
#pragma unroll
        for (int ni = 0; ni < 4; ni++) {
          const int col = colBase + wn * 64 + ni * 16 + l15;
          const float e = __expf((acc[mi][ni][r] - 1.0f) * INV_T);
          rs += (row == col) ? 0.0f : e;
        }
        rs = dpp_shr_add<DPP_ROW_SHR1>(rs);
        rs = dpp_shr_add<DPP_ROW_SHR2>(rs);
        rs = dpp_shr_add<DPP_ROW_SHR4>(rs);
        rs = dpp_shr_add<DPP_ROW_SHR8>(rs);
        if (l15 == 15) atomicAdd(&tsum[row], rs);
      }
  } else {
    float csum[4] = {0.f, 0.f, 0.f, 0.f};
#pragma unroll
    for (int mi = 0; mi < 4; mi++)
#pragma unroll
      for (int r = 0; r < 4; r++) {
        const int row = rowBase + wm * 64 + mi * 16 + quad * 4 + r;
        float rs = 0.0f;
#pragma unroll
        for (int ni = 0; ni < 4; ni++) {
          const float e = __expf((acc[mi][ni][r] - 1.0f) * INV_T);
          rs += e;
          csum[ni] += e;
        }
        rs = dpp_shr_add<DPP_ROW_SHR1>(rs);
        rs = dpp_shr_add<DPP_ROW_SHR2>(rs);
        rs = dpp_shr_add<DPP_ROW_SHR4>(rs);
        rs = dpp_shr_add<DPP_ROW_SHR8>(rs);
        if (l15 == 15) atomicAdd(&tsum[row], rs);
      }
#pragma unroll
    for (int ni = 0; ni < 4; ni++) {
      csum[ni] += __shfl_xor(csum[ni], 16);
      csum[ni] += __shfl_xor(csum[ni], 32);
      if (quad == 0) atomicAdd(&tsum[colBase + wn * 64 + ni * 16 + l15], csum[ni]);
    }
  }
}

// ---- launcher --------------------------------------------------------------
extern "C" void kernel_launch(void* const* d_in, const int* in_sizes, int n_in,
                              void* d_out, int out_size, void* d_ws, size_t ws_size,
                              hipStream_t stream) {
  const float* X = (const float*)d_in[0];
  float* out = (float*)d_out;

  float* tsum = (float*)d_ws;                       // 8192 fp32 = 32 KB
  u8* Xn = (u8*)d_ws + 65536;                       // 8192x512 fp8 = 4 MB

  void* args[] = {(void*)&X, (void*)&Xn, (void*)&tsum, (void*)&out};
  hipError_t err = hipLaunchCooperativeKernel(
      (const void*)fused_kernel, dim3(GRIDB), dim3(256), args, 0, stream);
  if (err != hipSuccess) {
    // fallback: 3-launch path (R0-equivalent)
    normalize_kernel<<<N_TOT / 4, 256, 0, stream>>>(X, Xn, tsum, out);
    gemm_fallback<<<NTRI, 256, 0, stream>>>(Xn, tsum);
    finalize_kernel<<<N_TOT / 256, 256, 0, stream>>>(tsum, out);
  }
}